// Round 5
// baseline (9596.219 us; speedup 1.0000x reference)
//
#include <hip/hip_runtime.h>
#include <hip/hip_fp16.h>

typedef _Float16 h16;
typedef _Float16 v8h  __attribute__((ext_vector_type(8)));
typedef float    v4f  __attribute__((ext_vector_type(4)));
typedef unsigned int v4u __attribute__((ext_vector_type(4)));

#define NPROD 16u
#define FASTW (1 << 14)     // fast-window polls before sticky-agent fallback (~2 ms)
#define BUDGET0 (1 << 18)   // total poll budget per thread (~35 ms hard cap, no hangs)

struct PParams {
  const float* x;                 // [64][512][256] fp32
  const float* Wih[4];            // [2048][KIN]
  const float* Whh[4];            // [2048][512]
  const float* bih[4];
  const float* bhh[4];
  h16* s[4];                      // streams: l=0..2 [512][64][512], l=3 [2][64][512]
  unsigned int* selfL;            // [16][512] local (own-XCD L2) flags
  unsigned int* selfA;            // [16][512] agent (MALL) flags
  unsigned int* claim;            // [8*32] per-XCD role claim, 128B stride
};

__device__ inline float fsigmoid(float x){
  float e = __builtin_amdgcn_exp2f(-1.4426950408889634f * __builtin_fabsf(x));
  float r = __builtin_amdgcn_rcpf(1.0f + e);
  return x >= 0.f ? r : e * r;
}
__device__ inline float ftanhf(float x){
  float e = __builtin_amdgcn_exp2f(-2.8853900817779268f * __builtin_fabsf(x));
  float t = (1.0f - e) * __builtin_amdgcn_rcpf(1.0f + e);
  return x >= 0.f ? t : -t;
}

// sc0-only load: bypass L1, served by this XCD's L2.
__device__ inline unsigned int poll_ld_sc0(const unsigned int* p){
  unsigned int r;
  asm volatile("global_load_dword %0, %1, off sc0\n\ts_waitcnt vmcnt(0)"
               : "=v"(r) : "v"(p) : "memory");
  return r;
}
// Plain L2 atomic add (no return, no sc bits -> executes in own XCD's L2).
__device__ inline void atomic_add_l2(unsigned int* p, unsigned int v){
  asm volatile("global_atomic_add %0, %1, off" :: "v"(p), "v"(v) : "memory");
}
// Issue 4x16B loads without waiting. SC1: read through to MALL (cross-XCD safe).
template<bool SC1>
__device__ inline void issue_ld4(v4u& r0, v4u& r1, v4u& r2, v4u& r3,
                                 const void* p0, const void* p1,
                                 const void* p2, const void* p3){
  if (SC1)
    asm volatile(
      "global_load_dwordx4 %0, %4, off sc0 sc1\n\t"
      "global_load_dwordx4 %1, %5, off sc0 sc1\n\t"
      "global_load_dwordx4 %2, %6, off sc0 sc1\n\t"
      "global_load_dwordx4 %3, %7, off sc0 sc1"
      : "=&v"(r0), "=&v"(r1), "=&v"(r2), "=&v"(r3)
      : "v"(p0), "v"(p1), "v"(p2), "v"(p3));
  else
    asm volatile(
      "global_load_dwordx4 %0, %4, off sc0\n\t"
      "global_load_dwordx4 %1, %5, off sc0\n\t"
      "global_load_dwordx4 %2, %6, off sc0\n\t"
      "global_load_dwordx4 %3, %7, off sc0"
      : "=&v"(r0), "=&v"(r1), "=&v"(r2), "=&v"(r3)
      : "v"(p0), "v"(p1), "v"(p2), "v"(p3));
}
// Drain outstanding vmem; memory clobber orders all later memory ops after it.
__device__ inline void wait_vm0(){
  asm volatile("s_waitcnt vmcnt(0)" ::: "memory");
}

// Dual-path wait. Returns true if the consumer must use the agent (MALL) data
// path. Sticky: once the local fast window times out, stay agent forever.
__device__ inline bool wait_dual(const unsigned int* fl, const unsigned int* fa,
                                 bool& sticky, int& budget){
  if (!sticky){
    int w = 0;
    for (;;){
      if (poll_ld_sc0(fl) >= NPROD) return false;
      __builtin_amdgcn_s_sleep(1);
      if (--budget <= 0) return false;       // budget gone: proceed, terminate
      if (++w >= FASTW){ sticky = true; break; }
    }
  }
  while (__hip_atomic_load(fa, __ATOMIC_RELAXED, __HIP_MEMORY_SCOPE_AGENT) < NPROD){
    __builtin_amdgcn_s_sleep(1);
    if (--budget <= 0) break;
  }
  return true;
}

// LDS layout f(row, c) = (c>>2)*512 + (c&3)*128 + row*8 (halves), c = 16B chunk.
// Staging writes (tid*8 + i*2048) and fragment reads (lane*8 + kk*512) are both
// wave-contiguous 1KB -> conflict-free (m134 pattern).
// MODE: 0 = x input (layer 0), 1 = same-XCD src, 2 = cross-XCD src (agent path).
template<int KIN, int MODE>
__device__ void run_layer(const float* __restrict__ Wih, const float* __restrict__ Whh,
                          const float* __restrict__ bih, const float* __restrict__ bhh,
                          const float* __restrict__ xsrc,
                          const h16* __restrict__ src,
                          h16* __restrict__ dst, int dstMask,
                          unsigned int* selfLf, unsigned int* selfAf,
                          const unsigned int* srcLf, const unsigned int* srcAf,
                          int rg, int bg, h16* A)
{
  const int tid  = threadIdx.x;
  const int wv   = tid >> 6;
  const int lane = tid & 63;
  const int KI   = KIN / 32;
  const int HOFF = 8192;

  const int n16  = lane & 15;
  const int q4   = lane >> 4;
  const int unit = rg*32 + wv*8 + (n16 & 7);
  const int row0 = ((n16 >> 3)    ) * 512 + unit;   // gates i / f
  const int row1 = ((n16 >> 3) + 2) * 512 + unit;   // gates g / o

  // staging geometry: thread covers global row srow, halves scol8 + i*128
  const int srow  = tid & 15;
  const int scol8 = (((tid >> 6) * 4) + ((tid >> 4) & 3)) * 8;

  // ---- prologue: weight slices -> register fragments (one-time)
  v8h wihf[KI][2];
  v8h whhf[16][2];
  #pragma unroll
  for (int kk = 0; kk < KI; ++kk)
    #pragma unroll
    for (int j = 0; j < 2; ++j){
      const float* p = Wih + (size_t)(j ? row1 : row0) * KIN + kk*32 + q4*8;
      v8h fr;
      #pragma unroll
      for (int e = 0; e < 8; ++e) fr[e] = (h16)p[e];
      wihf[kk][j] = fr;
    }
  #pragma unroll
  for (int kk = 0; kk < 16; ++kk)
    #pragma unroll
    for (int j = 0; j < 2; ++j){
      const float* p = Whh + (size_t)(j ? row1 : row0) * 512 + kk*32 + q4*8;
      v8h fr;
      #pragma unroll
      for (int e = 0; e < 8; ++e) fr[e] = (h16)p[e];
      whhf[kk][j] = fr;
    }
  const float bias0 = bih[row0] + bhh[row0];
  const float bias1 = bih[row1] + bhh[row1];
  float c[4] = {0.f, 0.f, 0.f, 0.f};
  const bool hi = (lane & 8) != 0;

  int  budget = BUDGET0;
  bool agSelf = false;
  bool agSrc  = (MODE == 2);

  // ---- prefetch t = 0
  v4u pf0, pf1, pf2, pf3;
  float4 xa0, xa1, xa2, xa3;
  if (MODE == 0){
    const float* xb = xsrc + ((size_t)(bg*16 + srow)*512 + 0)*256 + scol8;
    xa0 = ((const float4*)xb)[0];        xa1 = ((const float4*)xb)[1];
    xa2 = ((const float4*)(xb + 128))[0]; xa3 = ((const float4*)(xb + 128))[1];
  } else {
    bool am = wait_dual(srcLf + 0, srcAf + 0, agSrc, budget);
    const h16* sb = src + ((size_t)(bg*16 + srow))*512 + scol8;
    if (am) issue_ld4<true >(pf0, pf1, pf2, pf3, sb, sb+128, sb+256, sb+384);
    else    issue_ld4<false>(pf0, pf1, pf2, pf3, sb, sb+128, sb+256, sb+384);
  }

  h16* const Ast = A + tid*8;
  h16* const Ahw = A + HOFF + tid*8;
  const h16* const Ain = A + lane*8;
  const h16* const Ahr = A + HOFF + lane*8;

  #pragma unroll 1
  for (int t = 0; t < 512; ++t){
    // ---- B: stage src(t) -> LDS in-region
    if (MODE == 0){
      v8h o0 = {(h16)xa0.x,(h16)xa0.y,(h16)xa0.z,(h16)xa0.w,
                (h16)xa1.x,(h16)xa1.y,(h16)xa1.z,(h16)xa1.w};
      v8h o1 = {(h16)xa2.x,(h16)xa2.y,(h16)xa2.z,(h16)xa2.w,
                (h16)xa3.x,(h16)xa3.y,(h16)xa3.z,(h16)xa3.w};
      *(v8h*)(Ast)        = o0;
      *(v8h*)(Ast + 2048) = o1;
    } else {
      wait_vm0();
      *(v4u*)(Ast)        = pf0;
      *(v4u*)(Ast + 2048) = pf1;
      *(v4u*)(Ast + 4096) = pf2;
      *(v4u*)(Ast + 6144) = pf3;
    }
    __syncthreads();

    // ---- C1: input-weight MFMAs
    v4f acc0 = {0.f,0.f,0.f,0.f};
    v4f acc1 = {0.f,0.f,0.f,0.f};
    #pragma unroll
    for (int kk = 0; kk < KI; ++kk){
      v8h a = *(const v8h*)(Ain + kk*512);
      acc0 = __builtin_amdgcn_mfma_f32_16x16x32_f16(a, wihf[kk][0], acc0, 0, 0, 0);
      acc1 = __builtin_amdgcn_mfma_f32_16x16x32_f16(a, wihf[kk][1], acc1, 0, 0, 0);
    }

    // ---- A: self h(t-1) -> LDS h-region
    if (t > 0){
      bool am = wait_dual(selfLf + (t-1), selfAf + (t-1), agSelf, budget);
      const h16* hb = dst + ((size_t)((t-1) & dstMask)*64 + bg*16 + srow)*512 + scol8;
      v4u h0, h1, h2, h3;
      if (am) issue_ld4<true >(h0, h1, h2, h3, hb, hb+128, hb+256, hb+384);
      else    issue_ld4<false>(h0, h1, h2, h3, hb, hb+128, hb+256, hb+384);
      wait_vm0();
      *(v4u*)(Ahw)        = h0;
      *(v4u*)(Ahw + 2048) = h1;
      *(v4u*)(Ahw + 4096) = h2;
      *(v4u*)(Ahw + 6144) = h3;
    } else {
      v4u z = {0u,0u,0u,0u};
      *(v4u*)(Ahw)        = z;
      *(v4u*)(Ahw + 2048) = z;
      *(v4u*)(Ahw + 4096) = z;
      *(v4u*)(Ahw + 6144) = z;
    }
    __syncthreads();

    // ---- C2: recurrent-weight MFMAs
    #pragma unroll
    for (int kk = 0; kk < 16; ++kk){
      v8h a = *(const v8h*)(Ahr + kk*512);
      acc0 = __builtin_amdgcn_mfma_f32_16x16x32_f16(a, whhf[kk][0], acc0, 0, 0, 0);
      acc1 = __builtin_amdgcn_mfma_f32_16x16x32_f16(a, whhf[kk][1], acc1, 0, 0, 0);
    }

    // ---- D: gates; lane L holds (i|f) in acc0, (g|o) in acc1; partner L^8
    h16* drow = dst + (size_t)(t & dstMask) * 64 * 512;
    #pragma unroll
    for (int r = 0; r < 4; ++r){
      float z0 = acc0[r] + bias0;
      float z1 = acc1[r] + bias1;
      float p0 = __shfl_xor(z0, 8, 64);
      float p1 = __shfl_xor(z1, 8, 64);
      float iv = hi ? p0 : z0;
      float fv = hi ? z0 : p0;
      float gv = hi ? p1 : z1;
      float ov = hi ? z1 : p1;
      iv = fsigmoid(iv); fv = fsigmoid(fv); ov = fsigmoid(ov);
      gv = ftanhf(gv);
      c[r] = fv * c[r] + iv * gv;
      float hval = ov * ftanhf(c[r]);
      h16 hh = (h16)hval;
      unsigned int mine = (unsigned int)__builtin_bit_cast(unsigned short, hh);
      unsigned int partner = (unsigned int)__shfl_xor((int)mine, 1, 64);
      if (!hi && !(n16 & 1)){
        int batch = bg*16 + q4*4 + r;
        unsigned int* gp = (unsigned int*)(drow + (size_t)batch*512 + unit);
        unsigned int pk = mine | (partner << 16);
        *(volatile unsigned int*)gp = pk;                       // own-XCD L2
        __hip_atomic_store(gp, pk, __ATOMIC_RELAXED,
                           __HIP_MEMORY_SCOPE_AGENT);           // through to MALL
      }
    }
    __syncthreads();   // compiler drains vmcnt(0) for tracked stores before barrier

    if (tid == 0){
      atomic_add_l2(selfLf + t, 1u);                            // local flag (L2)
      __hip_atomic_fetch_add(selfAf + t, 1u, __ATOMIC_RELAXED,
                             __HIP_MEMORY_SCOPE_AGENT);         // agent flag (MALL)
    }

    // ---- E: prefetch src(t+1)
    if (t < 511){
      if (MODE == 0){
        const float* xb = xsrc + ((size_t)(bg*16 + srow)*512 + (t+1))*256 + scol8;
        xa0 = ((const float4*)xb)[0];        xa1 = ((const float4*)xb)[1];
        xa2 = ((const float4*)(xb + 128))[0]; xa3 = ((const float4*)(xb + 128))[1];
      } else {
        bool am = wait_dual(srcLf + (t+1), srcAf + (t+1), agSrc, budget);
        const h16* sb = src + ((size_t)(t+1)*64 + bg*16 + srow)*512 + scol8;
        if (am) issue_ld4<true >(pf0, pf1, pf2, pf3, sb, sb+128, sb+256, sb+384);
        else    issue_ld4<false>(pf0, pf1, pf2, pf3, sb, sb+128, sb+256, sb+384);
      }
    }
  }
}

__global__ __launch_bounds__(256, 1) void lstm_persist(PParams p){
  // 84 KB static LDS (32 KB used) forces 1 wg/CU => exactly 32 wgs per XCD.
  __shared__ h16 A[43008];
  __shared__ int roleS;
  if (threadIdx.x == 0){
    unsigned int xcc;
    asm volatile("s_getreg_b32 %0, hwreg(HW_REG_XCC_ID)" : "=s"(xcc));
    xcc &= 7u;
    int role = -1;
    // capacity-checked claim with overflow scan: every wg gets a unique role
    for (int i = 0; i < 8 && role < 0; ++i){
      unsigned int x = (xcc + (unsigned)i) & 7u;
      unsigned int s = __hip_atomic_fetch_add(p.claim + x*32, 1u, __ATOMIC_RELAXED,
                                              __HIP_MEMORY_SCOPE_AGENT);
      if (s < 32u) role = (int)(x*32u + s);
    }
    if (role < 0) role = 0;   // unreachable (256 grants for 256 wgs)
    roleS = role;
  }
  __syncthreads();
  const int role = roleS;
  const int xcd  = role >> 5;
  const int slot = role & 31;
  const int bg   = xcd >> 1;                       // 4 batch groups x 2 XCDs each
  const int layer = ((xcd & 1) << 1) + (slot & 1); // even XCD: l0,l1; odd: l2,l3
  const int rg   = slot >> 1;                      // 16 row-groups per layer

  unsigned int* sl = p.selfL + (size_t)(layer*4 + bg) * 512;
  unsigned int* sa = p.selfA + (size_t)(layer*4 + bg) * 512;
  if (layer == 0){
    run_layer<256, 0>(p.Wih[0], p.Whh[0], p.bih[0], p.bhh[0], p.x, nullptr,
                      p.s[0], 511, sl, sa, nullptr, nullptr, rg, bg, A);
  } else {
    const unsigned int* pl = p.selfL + (size_t)((layer-1)*4 + bg) * 512;
    const unsigned int* pa = p.selfA + (size_t)((layer-1)*4 + bg) * 512;
    if (layer == 1)
      run_layer<512, 1>(p.Wih[1], p.Whh[1], p.bih[1], p.bhh[1], nullptr, p.s[0],
                        p.s[1], 511, sl, sa, pl, pa, rg, bg, A);
    else if (layer == 2)
      run_layer<512, 2>(p.Wih[2], p.Whh[2], p.bih[2], p.bhh[2], nullptr, p.s[1],
                        p.s[2], 511, sl, sa, pl, pa, rg, bg, A);
    else
      run_layer<512, 1>(p.Wih[3], p.Whh[3], p.bih[3], p.bhh[3], nullptr, p.s[2],
                        p.s[3], 1, sl, sa, pl, pa, rg, bg, A);
  }
}

__global__ void head_k(const h16* __restrict__ h3, const float* __restrict__ Wo,
                       const float* __restrict__ bo, float* __restrict__ out){
  const int b = blockIdx.x;
  const int lane = threadIdx.x;
  float s = 0.f;
  for (int u = lane; u < 512; u += 64)
    s += (float)h3[(size_t)b * 512 + u] * Wo[u];
  #pragma unroll
  for (int off = 32; off; off >>= 1) s += __shfl_down(s, off, 64);
  if (lane == 0) out[b] = s + bo[0];
}

__global__ void zero_out_k(float* out, int n){
  int i = blockIdx.x * 64 + threadIdx.x;
  if (i < n) out[i] = 0.f;
}

extern "C" void kernel_launch(void* const* d_in, const int* in_sizes, int n_in,
                              void* d_out, int out_size, void* d_ws, size_t ws_size,
                              hipStream_t stream){
  PParams p;
  p.x = (const float*)d_in[0];
  for (int l = 0; l < 4; ++l){
    p.Wih[l] = (const float*)d_in[1 + 4*l + 0];
    p.Whh[l] = (const float*)d_in[1 + 4*l + 1];
    p.bih[l] = (const float*)d_in[1 + 4*l + 2];
    p.bhh[l] = (const float*)d_in[1 + 4*l + 3];
  }
  const float* Wo = (const float*)d_in[17];
  const float* bo = (const float*)d_in[18];

  const size_t CTRL   = 131072;  // selfL 32K + selfA 32K + claim 1K + pad
  const size_t SBYTES = (size_t)512 * 64 * 512 * 2;   // 32 MB per full stream
  const size_t NEED   = CTRL + 3 * SBYTES + (size_t)2 * 64 * 512 * 2;

  if (ws_size < NEED){
    zero_out_k<<<dim3(1), dim3(64), 0, stream>>>((float*)d_out, out_size);
    return;
  }

  char* ws = (char*)d_ws;
  p.selfL = (unsigned int*)ws;                  // 16*512*4 = 32768
  p.selfA = (unsigned int*)(ws + 32768);        // 16*512*4 = 32768
  p.claim = (unsigned int*)(ws + 65536);        // 8 counters, 128B stride
  size_t off = CTRL;
  for (int l = 0; l < 3; ++l){ p.s[l] = (h16*)(ws + off); off += SBYTES; }
  p.s[3] = (h16*)(ws + off);

  (void)hipMemsetAsync(ws, 0, CTRL, stream);

  void* args[] = { &p };
  hipError_t e = hipLaunchCooperativeKernel((void*)lstm_persist, dim3(256), dim3(256),
                                            args, 0, stream);
  if (e != hipSuccess){
    lstm_persist<<<dim3(256), dim3(256), 0, stream>>>(p);
  }

  // final timestep t=511 lives in s3 slab (511 & 1) == 1
  head_k<<<dim3(64), dim3(64), 0, stream>>>(p.s[3] + (size_t)64 * 512, Wo, bo, (float*)d_out);
}

// Round 6
// 2073.794 us; speedup vs baseline: 4.6274x; 4.6274x over previous
//
#include <hip/hip_runtime.h>
#include <hip/hip_fp16.h>

typedef _Float16 h16;
typedef _Float16 v8h  __attribute__((ext_vector_type(8)));
typedef float    v4f  __attribute__((ext_vector_type(4)));
typedef unsigned int v4u __attribute__((ext_vector_type(4)));

#define SENTU 0x7C7C7C7Cu   // fp16 NaN pair: unreachable by sigmoid/tanh gate math
#define CAP   (1 << 13)     // per-wait retry cap (~few ms worst case, no hangs)

struct PParams {
  const float* x;                 // [64][512][256] fp32
  const float* Wih[4];            // [2048][KIN]
  const float* Whh[4];            // [2048][512]
  const float* bih[4];
  const float* bhh[4];
  h16* s0; h16* s1; h16* s2;      // full streams [512][64][512] h16 (write-once slots)
  h16* s3;                        // ring [8][64][512] h16 (producer re-sentinels t+4)
};

__device__ inline float fsigmoid(float x){
  float e = __builtin_amdgcn_exp2f(-1.4426950408889634f * __builtin_fabsf(x));
  float r = __builtin_amdgcn_rcpf(1.0f + e);
  return x >= 0.f ? r : e * r;
}
__device__ inline float ftanhf(float x){
  float e = __builtin_amdgcn_exp2f(-2.8853900817779268f * __builtin_fabsf(x));
  float t = (1.0f - e) * __builtin_amdgcn_rcpf(1.0f + e);
  return x >= 0.f ? t : -t;
}

// Issue 4x16B agent-coherent loads (sc0 sc1: bypass L1/L2, served by MALL —
// the R2/R5-proven cross-XCD visibility path) without waiting.
__device__ inline void issue_ld4(v4u& r0, v4u& r1, v4u& r2, v4u& r3,
                                 const void* p0, const void* p1,
                                 const void* p2, const void* p3){
  asm volatile(
    "global_load_dwordx4 %0, %4, off sc0 sc1\n\t"
    "global_load_dwordx4 %1, %5, off sc0 sc1\n\t"
    "global_load_dwordx4 %2, %6, off sc0 sc1\n\t"
    "global_load_dwordx4 %3, %7, off sc0 sc1"
    : "=&v"(r0), "=&v"(r1), "=&v"(r2), "=&v"(r3)
    : "v"(p0), "v"(p1), "v"(p2), "v"(p3));
}
// Drain ALL outstanding vmem (safe regardless of compiler-scheduled vmem).
__device__ inline void wait_vm0(){
  asm volatile("s_waitcnt vmcnt(0)" ::: "memory");
}
// Agent-coherent write-through store (visible at MALL).
__device__ inline void st_agent(void* p, unsigned int v){
  asm volatile("global_store_dword %0, %1, off sc0 sc1" :: "v"(p), "v"(v) : "memory");
}
__device__ inline bool dirtyv(v4u a, v4u b, v4u c, v4u d){
  int bad = 0;
  #pragma unroll
  for (int i = 0; i < 4; ++i)
    bad |= (a[i] == SENTU) | (b[i] == SENTU) | (c[i] == SENTU) | (d[i] == SENTU);
  return bad != 0;
}

// LDS layout f(row, c) = (c>>2)*512 + (c&3)*128 + row*8 (halves), c = 16B chunk.
// Staging writes (tid*8 + i*2048) and fragment reads (lane*8 + kk*512) are both
// wave-contiguous 1KB -> conflict-free (R5 measured: SQ_LDS_BANK_CONFLICT = 0).
// MODE: 0 = x input (layer 0), 1 = sentinel-checked h16 stream src.
// RESENT: dst is an 8-slot ring; producer re-sentinels slot t+4.
template<int KIN, int MODE, bool RESENT>
__device__ void run_layer(const float* __restrict__ Wih, const float* __restrict__ Whh,
                          const float* __restrict__ bih, const float* __restrict__ bhh,
                          const float* __restrict__ xsrc,
                          const h16* __restrict__ src,
                          h16* __restrict__ dst, int dstMask,
                          int rg, int bg, h16* A)
{
  const int tid  = threadIdx.x;
  const int wv   = tid >> 6;
  const int lane = tid & 63;
  const int KI   = KIN / 32;
  const int HOFF = 8192;

  const int n16  = lane & 15;
  const int q4   = lane >> 4;
  const int unit = rg*32 + wv*8 + (n16 & 7);
  const int row0 = ((n16 >> 3)    ) * 512 + unit;   // gates i / f
  const int row1 = ((n16 >> 3) + 2) * 512 + unit;   // gates g / o

  const int srow  = tid & 15;        // staged global row
  const int g     = tid >> 4;        // column group 0..15
  const int scol8 = g * 8;           // halves

  // ---- prologue: weight slices -> register fragments (one-time)
  v8h wihf[KI][2];
  v8h whhf[16][2];
  #pragma unroll
  for (int kk = 0; kk < KI; ++kk)
    #pragma unroll
    for (int j = 0; j < 2; ++j){
      const float* p = Wih + (size_t)(j ? row1 : row0) * KIN + kk*32 + q4*8;
      v8h fr;
      #pragma unroll
      for (int e = 0; e < 8; ++e) fr[e] = (h16)p[e];
      wihf[kk][j] = fr;
    }
  #pragma unroll
  for (int kk = 0; kk < 16; ++kk)
    #pragma unroll
    for (int j = 0; j < 2; ++j){
      const float* p = Whh + (size_t)(j ? row1 : row0) * 512 + kk*32 + q4*8;
      v8h fr;
      #pragma unroll
      for (int e = 0; e < 8; ++e) fr[e] = (h16)p[e];
      whhf[kk][j] = fr;
    }
  const float bias0 = bih[row0] + bhh[row0];
  const float bias1 = bih[row1] + bhh[row1];
  float c[4] = {0.f, 0.f, 0.f, 0.f};
  const bool hi = (lane & 8) != 0;

  v4u sp0{}, sp1{}, sp2{}, sp3{};   // src prefetch regs
  v4u hf0{}, hf1{}, hf2{}, hf3{};   // self h prefetch regs

  // ---- prologue prefetch of src(0); drained immediately (one-time cost)
  if (MODE == 0){
    const float* xb = xsrc + ((size_t)(bg*16 + srow)*512 + 0)*256 + g*8;
    issue_ld4(sp0, sp1, sp2, sp3, xb, xb + 4, xb + 128, xb + 132);
  } else {
    const h16* sb = src + ((size_t)(bg*16 + srow))*512 + scol8;
    issue_ld4(sp0, sp1, sp2, sp3, sb, sb + 128, sb + 256, sb + 384);
  }
  wait_vm0();

  h16* const Ast = A + tid*8;
  h16* const Ahw = A + HOFF + tid*8;
  const h16* const Ain = A + lane*8;
  const h16* const Ahr = A + HOFF + lane*8;

  #pragma unroll 1
  for (int t = 0; t < 512; ++t){
    // ---- B: stage src(t) -> LDS in-region (regs already final)
    if (MODE == 0){
      v4f f0 = __builtin_bit_cast(v4f, sp0);
      v4f f1 = __builtin_bit_cast(v4f, sp1);
      v4f f2 = __builtin_bit_cast(v4f, sp2);
      v4f f3 = __builtin_bit_cast(v4f, sp3);
      v8h o0 = {(h16)f0[0],(h16)f0[1],(h16)f0[2],(h16)f0[3],
                (h16)f1[0],(h16)f1[1],(h16)f1[2],(h16)f1[3]};
      v8h o1 = {(h16)f2[0],(h16)f2[1],(h16)f2[2],(h16)f2[3],
                (h16)f3[0],(h16)f3[1],(h16)f3[2],(h16)f3[3]};
      *(v8h*)(Ast)        = o0;
      *(v8h*)(Ast + 2048) = o1;
    } else {
      const h16* sb = src + ((size_t)t*64 + bg*16 + srow)*512 + scol8;
      int it = 0;
      while (dirtyv(sp0, sp1, sp2, sp3)){
        __builtin_amdgcn_s_sleep(4);
        issue_ld4(sp0, sp1, sp2, sp3, sb, sb + 128, sb + 256, sb + 384);
        wait_vm0();
        if (++it > CAP) break;
      }
      *(v4u*)(Ast)        = sp0;
      *(v4u*)(Ast + 2048) = sp1;
      *(v4u*)(Ast + 4096) = sp2;
      *(v4u*)(Ast + 6144) = sp3;
    }
    // issue src(t+1) prefetch (flight hides under the whole step)
    if (t < 511){
      if (MODE == 0){
        const float* xb = xsrc + ((size_t)(bg*16 + srow)*512 + (t+1))*256 + g*8;
        issue_ld4(sp0, sp1, sp2, sp3, xb, xb + 4, xb + 128, xb + 132);
      } else {
        const h16* sb = src + ((size_t)(t+1)*64 + bg*16 + srow)*512 + scol8;
        issue_ld4(sp0, sp1, sp2, sp3, sb, sb + 128, sb + 256, sb + 384);
      }
    }
    // speculative self h(t-1) load; flight hides under barrier + C1
    if (t > 0){
      const h16* hb = dst + ((size_t)((t-1) & dstMask)*64 + bg*16 + srow)*512 + scol8;
      issue_ld4(hf0, hf1, hf2, hf3, hb, hb + 128, hb + 256, hb + 384);
    }
    __syncthreads();

    // ---- C1: input-weight MFMAs
    v4f acc0 = {0.f,0.f,0.f,0.f};
    v4f acc1 = {0.f,0.f,0.f,0.f};
    #pragma unroll
    for (int kk = 0; kk < KI; ++kk){
      v8h a = *(const v8h*)(Ain + kk*512);
      acc0 = __builtin_amdgcn_mfma_f32_16x16x32_f16(a, wihf[kk][0], acc0, 0, 0, 0);
      acc1 = __builtin_amdgcn_mfma_f32_16x16x32_f16(a, wihf[kk][1], acc1, 0, 0, 0);
    }

    // ---- self phase: finalize h(t-1) regs (drains self + next-src loads)
    wait_vm0();
    if (t > 0){
      const h16* hb = dst + ((size_t)((t-1) & dstMask)*64 + bg*16 + srow)*512 + scol8;
      int it = 0;
      while (dirtyv(hf0, hf1, hf2, hf3)){
        __builtin_amdgcn_s_sleep(4);
        issue_ld4(hf0, hf1, hf2, hf3, hb, hb + 128, hb + 256, hb + 384);
        wait_vm0();
        if (++it > CAP) break;
      }
      *(v4u*)(Ahw)        = hf0;
      *(v4u*)(Ahw + 2048) = hf1;
      *(v4u*)(Ahw + 4096) = hf2;
      *(v4u*)(Ahw + 6144) = hf3;
    } else {
      v4u z = {0u,0u,0u,0u};
      *(v4u*)(Ahw)        = z;
      *(v4u*)(Ahw + 2048) = z;
      *(v4u*)(Ahw + 4096) = z;
      *(v4u*)(Ahw + 6144) = z;
    }
    __syncthreads();

    // ---- C2: recurrent-weight MFMAs
    #pragma unroll
    for (int kk = 0; kk < 16; ++kk){
      v8h a = *(const v8h*)(Ahr + kk*512);
      acc0 = __builtin_amdgcn_mfma_f32_16x16x32_f16(a, whhf[kk][0], acc0, 0, 0, 0);
      acc1 = __builtin_amdgcn_mfma_f32_16x16x32_f16(a, whhf[kk][1], acc1, 0, 0, 0);
    }

    // ---- D: gates; lane L holds (i|f) in acc0, (g|o) in acc1; partner L^8
    h16* drow  = dst + (size_t)(t & dstMask) * (64*512);
    h16* dsent = RESENT ? dst + (size_t)((t+4) & dstMask) * (64*512) : nullptr;
    #pragma unroll
    for (int r = 0; r < 4; ++r){
      float z0 = acc0[r] + bias0;
      float z1 = acc1[r] + bias1;
      float p0 = __shfl_xor(z0, 8, 64);
      float p1 = __shfl_xor(z1, 8, 64);
      float iv = hi ? p0 : z0;
      float fv = hi ? z0 : p0;
      float gv = hi ? p1 : z1;
      float ov = hi ? z1 : p1;
      iv = fsigmoid(iv); fv = fsigmoid(fv); ov = fsigmoid(ov);
      gv = ftanhf(gv);
      c[r] = fv * c[r] + iv * gv;
      float hval = ov * ftanhf(c[r]);
      h16 hh = (h16)hval;
      unsigned int mine = (unsigned int)__builtin_bit_cast(unsigned short, hh);
      unsigned int partner = (unsigned int)__shfl_xor((int)mine, 1, 64);
      if (!hi && !(n16 & 1)){
        int batch = bg*16 + q4*4 + r;
        st_agent(drow + (size_t)batch*512 + unit, mine | (partner << 16));
        if (RESENT)
          st_agent(dsent + (size_t)batch*512 + unit, SENTU);
      }
    }
  }
}

__global__ __launch_bounds__(256, 1) void lstm_persist(PParams p){
  // 84 KB static LDS (32 KB used) forces 1 wg/CU -> all 256 wgs co-resident.
  __shared__ h16 A[43008];
  const int bx = blockIdx.x;
  const int l  = bx >> 6;
  const int rg = (bx >> 2) & 15;
  const int bg = bx & 3;
  if (l == 0)
    run_layer<256, 0, false>(p.Wih[0], p.Whh[0], p.bih[0], p.bhh[0], p.x, nullptr,
                             p.s0, 511, rg, bg, A);
  else if (l == 1)
    run_layer<512, 1, false>(p.Wih[1], p.Whh[1], p.bih[1], p.bhh[1], nullptr, p.s0,
                             p.s1, 511, rg, bg, A);
  else if (l == 2)
    run_layer<512, 1, false>(p.Wih[2], p.Whh[2], p.bih[2], p.bhh[2], nullptr, p.s1,
                             p.s2, 511, rg, bg, A);
  else
    run_layer<512, 1, true >(p.Wih[3], p.Whh[3], p.bih[3], p.bhh[3], nullptr, p.s2,
                             p.s3, 7, rg, bg, A);
}

__global__ void head_k(const h16* __restrict__ h3, const float* __restrict__ Wo,
                       const float* __restrict__ bo, float* __restrict__ out){
  const int b = blockIdx.x;
  const int lane = threadIdx.x;
  float s = 0.f;
  for (int u = lane; u < 512; u += 64)
    s += (float)h3[(size_t)b * 512 + u] * Wo[u];
  #pragma unroll
  for (int off = 32; off; off >>= 1) s += __shfl_down(s, off, 64);
  if (lane == 0) out[b] = s + bo[0];
}

__global__ void zero_out_k(float* out, int n){
  int i = blockIdx.x * 64 + threadIdx.x;
  if (i < n) out[i] = 0.f;
}

extern "C" void kernel_launch(void* const* d_in, const int* in_sizes, int n_in,
                              void* d_out, int out_size, void* d_ws, size_t ws_size,
                              hipStream_t stream){
  PParams p;
  p.x = (const float*)d_in[0];
  for (int l = 0; l < 4; ++l){
    p.Wih[l] = (const float*)d_in[1 + 4*l + 0];
    p.Whh[l] = (const float*)d_in[1 + 4*l + 1];
    p.bih[l] = (const float*)d_in[1 + 4*l + 2];
    p.bhh[l] = (const float*)d_in[1 + 4*l + 3];
  }
  const float* Wo = (const float*)d_in[17];
  const float* bo = (const float*)d_in[18];

  const size_t SBYTES = (size_t)512 * 64 * 512 * 2;   // 32 MiB full stream
  const size_t RBYTES = (size_t)8   * 64 * 512 * 2;   // 512 KiB l3 ring
  const size_t NEED   = 3 * SBYTES + RBYTES;

  if (ws_size < NEED){
    zero_out_k<<<dim3(1), dim3(64), 0, stream>>>((float*)d_out, out_size);
    return;
  }

  char* ws = (char*)d_ws;
  p.s0 = (h16*)(ws);
  p.s1 = (h16*)(ws + SBYTES);
  p.s2 = (h16*)(ws + 2*SBYTES);
  p.s3 = (h16*)(ws + 3*SBYTES);

  // Sentinel-fill all stream slots (0x7C7C = fp16 NaN, unreachable by gate math).
  (void)hipMemsetAsync(ws, 0x7C, NEED, stream);

  void* args[] = { &p };
  hipError_t e = hipLaunchCooperativeKernel((void*)lstm_persist, dim3(256), dim3(256),
                                            args, 0, stream);
  if (e != hipSuccess){
    // plain launch: 256 blocks at 1 wg/CU co-reside on 256 CUs anyway
    lstm_persist<<<dim3(256), dim3(256), 0, stream>>>(p);
  }

  // h3 at t=511 lives in ring slot 511 & 7 == 7
  head_k<<<dim3(64), dim3(64), 0, stream>>>(p.s3 + (size_t)7 * 64 * 512, Wo, bo,
                                            (float*)d_out);
}